// Round 16
// baseline (134.841 us; speedup 1.0000x reference)
//
#include <hip/hip_runtime.h>

#define HWPIX 4096   // 64*64 pixels
#define SEQ   77
#define NBLK_SELF 2048   // 2 rows (16KB each) per block

typedef float f32x4 __attribute__((ext_vector_type(4)));

// bilinear coord for 64 -> 256 upsample (align_corners=False), i in [0,255]
__device__ __forceinline__ void coord(int i, int& i0, int& i1, float& w) {
    float s = fminf(fmaxf(0.25f * (float)i - 0.375f, 0.0f), 63.0f);
    i0 = (int)s;              // s >= 0 so trunc == floor
    i1 = min(i0 + 1, 63);
    w = s - (float)i0;
}

// Kernel 1: blocks 0..63 = upsample-max partials (8 ch x 8 row-groups);
// blocks 64..71 = cross-attn MSE partials (independent of the max).
__global__ __launch_bounds__(256) void kmaxc(const float* __restrict__ attn,
                                             const float* __restrict__ attn_e,
                                             float* __restrict__ ws_maxpart,
                                             float* __restrict__ ws_crosspart) {
    const int t = threadIdx.x;
    if (blockIdx.x < 64) {
        __shared__ float tile[10 * 64];
        __shared__ float red[4];
        const int c = blockIdx.x >> 3;
        const int g = blockIdx.x & 7;
        const int tok = c + 1;
        const int ybase = 8 * g - 1;

        for (int idx = t; idx < 640; idx += 256) {
            int rr = idx >> 6, x = idx & 63;
            int y = min(max(ybase + rr, 0), 63);
            tile[idx] = attn[(y * 64 + x) * SEQ + tok];
        }
        __syncthreads();

        int x0, x1; float wx;
        coord(t, x0, x1, wx);
        float m = -1e30f;
        int cy0 = -99, cy1 = -99;
        float r0 = 0.f, r1 = 0.f;
        for (int i = 32 * g; i < 32 * g + 32; ++i) {
            int y0, y1; float wy;
            coord(i, y0, y1, wy);
            if (y0 != cy0 || y1 != cy1) {
                int l0 = y0 - ybase, l1 = y1 - ybase;
                if (y0 == cy1) r0 = r1;
                else r0 = tile[l0 * 64 + x0] * (1.f - wx) + tile[l0 * 64 + x1] * wx;
                if (y1 == y0) r1 = r0;
                else r1 = tile[l1 * 64 + x0] * (1.f - wx) + tile[l1 * 64 + x1] * wx;
                cy0 = y0; cy1 = y1;
            }
            m = fmaxf(m, r0 * (1.f - wy) + r1 * wy);
        }
        #pragma unroll
        for (int off = 1; off < 64; off <<= 1)
            m = fmaxf(m, __shfl_xor(m, off, 64));
        if ((t & 63) == 0) red[t >> 6] = m;
        __syncthreads();
        if (t == 0)
            ws_maxpart[blockIdx.x] = fmaxf(fmaxf(red[0], red[1]), fmaxf(red[2], red[3]));
    } else {
        __shared__ float red[4];
        const int tok = (int)blockIdx.x - 64 + 1;
        const bool is_tok = (tok == 2) || (tok == 5);
        float sum = 0.f;
        #pragma unroll
        for (int kk = 0; kk < 16; ++kk) {
            int p = t + kk * 256;
            float d = attn[p * SEQ + tok] - attn_e[p * SEQ + tok];
            sum += d * d;
        }
        #pragma unroll
        for (int off = 1; off < 64; off <<= 1) sum += __shfl_xor(sum, off, 64);
        if ((t & 63) == 0) red[t >> 6] = sum;
        __syncthreads();
        if (t == 0)
            ws_crosspart[tok - 1] =
                (is_tok ? -1.f : 1.f) * (red[0] + red[1] + red[2] + red[3]);
    }
}

// Kernel 2: 16 blocks write wj[j] = sum_c (+/-1)*gate[c,j] (full overwrite,
// no memset/atomics). Block 0 thread 0 also resets the kself done-counter
// (runs before kself every replay -> deterministic).
__global__ __launch_bounds__(256) void kgates(const float* __restrict__ attn,
                                              const float* __restrict__ ws_maxpart,
                                              float* __restrict__ wj,
                                              unsigned* __restrict__ ws_counter) {
    const int bid = blockIdx.x;
    const int t = threadIdx.x;
    if (bid == 0 && t == 0) ws_counter[0] = 0u;
    const int j = bid * 256 + t;
    const int y = j >> 6, x = j & 63;
    float acc = 0.f;
    #pragma unroll
    for (int c = 0; c < 8; ++c) {
        const int tok = c + 1;
        const bool is_tok = (tok == 2) || (tok == 5);
        float mx = ws_maxpart[c * 8];
        #pragma unroll
        for (int g = 1; g < 8; ++g) mx = fmaxf(mx, ws_maxpart[c * 8 + g]);
        const float lim = mx * (is_tok ? 0.85f : 0.95f);
        bool gate = false;
        #pragma unroll
        for (int di = 1; di <= 2; ++di) {
            int y0, y1; float wy;
            coord(4 * y + di, y0, y1, wy);
            #pragma unroll
            for (int dj = 1; dj <= 2; ++dj) {
                int xa, xb; float wxv;
                coord(4 * x + dj, xa, xb, wxv);
                float v00 = attn[(y0 * 64 + xa) * SEQ + tok];
                float v01 = attn[(y0 * 64 + xb) * SEQ + tok];
                float v10 = attn[(y1 * 64 + xa) * SEQ + tok];
                float v11 = attn[(y1 * 64 + xb) * SEQ + tok];
                float top = v00 * (1.f - wxv) + v01 * wxv;
                float bot = v10 * (1.f - wxv) + v11 * wxv;
                float u = top * (1.f - wy) + bot * wy;
                gate = gate || (u >= lim);
            }
        }
        if (gate) acc += is_tok ? -1.f : 1.f;
    }
    wj[j] = acc;
}

// Kernel 3: streaming pass (r12-best asm pipeline: wj+row0 clause, row1
// clause, vmcnt(8) split wait) + last-block finalize (replaces kfin).
__global__ __launch_bounds__(256) void kself(const float* __restrict__ a,
                                             const float* __restrict__ b,
                                             const float* __restrict__ wj,
                                             float* __restrict__ ws_partial,
                                             const float* __restrict__ ws_crosspart,
                                             unsigned* __restrict__ ws_counter,
                                             float* __restrict__ out) {
    __shared__ float red[4];
    __shared__ int last;
    const int t = threadIdx.x;
    const float* a0 = a + (size_t)blockIdx.x * 8192;
    const float* b0 = b + (size_t)blockIdx.x * 8192;
    const float* a1 = a0 + 4096;
    const float* b1 = b0 + 4096;
    const unsigned vo0 = (unsigned)t * 16u;
    const unsigned vo1 = vo0 + 4096u;
    const unsigned vo2 = vo0 + 8192u;
    const unsigned vo3 = vo0 + 12288u;
    f32x4 w0, w1, w2, w3, xa0, xa1, xa2, xa3, yb0, yb1, yb2, yb3;
    f32x4 xc0, xc1, xc2, xc3, yd0, yd1, yd2, yd3;
    asm volatile(   // blobA: wj (cached) + row0 (nt)
        "global_load_dwordx4 %0, %12, %16\n\t"
        "global_load_dwordx4 %1, %13, %16\n\t"
        "global_load_dwordx4 %2, %14, %16\n\t"
        "global_load_dwordx4 %3, %15, %16\n\t"
        "global_load_dwordx4 %4, %12, %17 nt\n\t"
        "global_load_dwordx4 %5, %13, %17 nt\n\t"
        "global_load_dwordx4 %6, %14, %17 nt\n\t"
        "global_load_dwordx4 %7, %15, %17 nt\n\t"
        "global_load_dwordx4 %8, %12, %18 nt\n\t"
        "global_load_dwordx4 %9, %13, %18 nt\n\t"
        "global_load_dwordx4 %10, %14, %18 nt\n\t"
        "global_load_dwordx4 %11, %15, %18 nt"
        : "=&v"(w0), "=&v"(w1), "=&v"(w2), "=&v"(w3),
          "=&v"(xa0), "=&v"(xa1), "=&v"(xa2), "=&v"(xa3),
          "=&v"(yb0), "=&v"(yb1), "=&v"(yb2), "=&v"(yb3)
        : "v"(vo0), "v"(vo1), "v"(vo2), "v"(vo3),
          "s"(wj), "s"(a0), "s"(b0));
    asm volatile(   // blobB: row1 (nt) + wait for wj+row0
        "global_load_dwordx4 %0, %8, %12 nt\n\t"
        "global_load_dwordx4 %1, %9, %12 nt\n\t"
        "global_load_dwordx4 %2, %10, %12 nt\n\t"
        "global_load_dwordx4 %3, %11, %12 nt\n\t"
        "global_load_dwordx4 %4, %8, %13 nt\n\t"
        "global_load_dwordx4 %5, %9, %13 nt\n\t"
        "global_load_dwordx4 %6, %10, %13 nt\n\t"
        "global_load_dwordx4 %7, %11, %13 nt\n\t"
        "s_waitcnt vmcnt(8)"
        : "=&v"(xc0), "=&v"(xc1), "=&v"(xc2), "=&v"(xc3),
          "=&v"(yd0), "=&v"(yd1), "=&v"(yd2), "=&v"(yd3)
        : "v"(vo0), "v"(vo1), "v"(vo2), "v"(vo3),
          "s"(a1), "s"(b1));
    __builtin_amdgcn_sched_barrier(0);
    float sum = 0.f;
    {   // row0
        float d0 = xa0.x - yb0.x, d1 = xa0.y - yb0.y, d2 = xa0.z - yb0.z, d3 = xa0.w - yb0.w;
        sum += w0.x * d0 * d0 + w0.y * d1 * d1 + w0.z * d2 * d2 + w0.w * d3 * d3;
        d0 = xa1.x - yb1.x; d1 = xa1.y - yb1.y; d2 = xa1.z - yb1.z; d3 = xa1.w - yb1.w;
        sum += w1.x * d0 * d0 + w1.y * d1 * d1 + w1.z * d2 * d2 + w1.w * d3 * d3;
        d0 = xa2.x - yb2.x; d1 = xa2.y - yb2.y; d2 = xa2.z - yb2.z; d3 = xa2.w - yb2.w;
        sum += w2.x * d0 * d0 + w2.y * d1 * d1 + w2.z * d2 * d2 + w2.w * d3 * d3;
        d0 = xa3.x - yb3.x; d1 = xa3.y - yb3.y; d2 = xa3.z - yb3.z; d3 = xa3.w - yb3.w;
        sum += w3.x * d0 * d0 + w3.y * d1 * d1 + w3.z * d2 * d2 + w3.w * d3 * d3;
    }
    asm volatile("s_waitcnt vmcnt(0)" ::: "memory");
    __builtin_amdgcn_sched_barrier(0);
    {   // row1 (same columns -> same w)
        float d0 = xc0.x - yd0.x, d1 = xc0.y - yd0.y, d2 = xc0.z - yd0.z, d3 = xc0.w - yd0.w;
        sum += w0.x * d0 * d0 + w0.y * d1 * d1 + w0.z * d2 * d2 + w0.w * d3 * d3;
        d0 = xc1.x - yd1.x; d1 = xc1.y - yd1.y; d2 = xc1.z - yd1.z; d3 = xc1.w - yd1.w;
        sum += w1.x * d0 * d0 + w1.y * d1 * d1 + w1.z * d2 * d2 + w1.w * d3 * d3;
        d0 = xc2.x - yd2.x; d1 = xc2.y - yd2.y; d2 = xc2.z - yd2.z; d3 = xc2.w - yd2.w;
        sum += w2.x * d0 * d0 + w2.y * d1 * d1 + w2.z * d2 * d2 + w2.w * d3 * d3;
        d0 = xc3.x - yd3.x; d1 = xc3.y - yd3.y; d2 = xc3.z - yd3.z; d3 = xc3.w - yd3.w;
        sum += w3.x * d0 * d0 + w3.y * d1 * d1 + w3.z * d2 * d2 + w3.w * d3 * d3;
    }
    #pragma unroll
    for (int off = 1; off < 64; off <<= 1) sum += __shfl_xor(sum, off, 64);
    if ((t & 63) == 0) red[t >> 6] = sum;
    __syncthreads();
    if (t == 0) {
        ws_partial[blockIdx.x] = red[0] + red[1] + red[2] + red[3];
        __threadfence();
        unsigned old = atomicAdd(ws_counter, 1u);
        last = (old == NBLK_SELF - 1) ? 1 : 0;
    }
    __syncthreads();
    if (last) {   // final reduction: order identical to the old kfin
        __threadfence();
        float fsum = 0.f;
        #pragma unroll
        for (int k = 0; k < 8; ++k) fsum += ws_partial[t + k * 256];
        #pragma unroll
        for (int off = 1; off < 64; off <<= 1) fsum += __shfl_xor(fsum, off, 64);
        if ((t & 63) == 0) red[t >> 6] = fsum;
        __syncthreads();
        if (t == 0) {
            float tot = red[0] + red[1] + red[2] + red[3];
            #pragma unroll
            for (int k = 0; k < 8; ++k) tot += ws_crosspart[k];
            out[0] = tot * (1.0f / HWPIX);
        }
    }
}

extern "C" void kernel_launch(void* const* d_in, const int* in_sizes, int n_in,
                              void* d_out, int out_size, void* d_ws, size_t ws_size,
                              hipStream_t stream) {
    const float* attn   = (const float*)d_in[0];
    const float* attn_e = (const float*)d_in[1];
    const float* sa     = (const float*)d_in[2];
    const float* sae    = (const float*)d_in[3];
    float* out = (float*)d_out;
    float*    wj      = (float*)d_ws;        // [0,    4096) gate weights (overwritten)
    float*    ws_maxp = wj + HWPIX;          // [4096, 4160) 64 max partials
    float*    ws_crop = wj + 4160;           // [4160, 4168) 8 cross partials
    unsigned* ws_cnt  = (unsigned*)(wj + 4168); // [4168) done-counter (reset by kgates)
    float*    ws_part = wj + 4352;           // [4352, 6400) kself partials (2048)

    // 3 launches; no memsets, no float atomics. Counter is reset by kgates
    // each replay before kself uses it.
    kmaxc <<<72,        256, 0, stream>>>(attn, attn_e, ws_maxp, ws_crop);
    kgates<<<16,        256, 0, stream>>>(attn, ws_maxp, wj, ws_cnt);
    kself <<<NBLK_SELF, 256, 0, stream>>>(sa, sae, wj, ws_part, ws_crop, ws_cnt, out);
}

// Round 17
// 36.320 us; speedup vs baseline: 3.7126x; 3.7126x over previous
//
#include <hip/hip_runtime.h>

#define HWPIX 4096   // 64*64 pixels
#define SEQ   77
#define NBLK_SELF 2048   // 2 rows (16KB each) per block

typedef float f32x4 __attribute__((ext_vector_type(4)));

// bilinear coord for 64 -> 256 upsample (align_corners=False), i in [0,255]
__device__ __forceinline__ void coord(int i, int& i0, int& i1, float& w) {
    float s = fminf(fmaxf(0.25f * (float)i - 0.375f, 0.0f), 63.0f);
    i0 = (int)s;              // s >= 0 so trunc == floor
    i1 = min(i0 + 1, 63);
    w = s - (float)i0;
}

// Kernel 1: blocks 0..63 = upsample-max partials (8 ch x 8 row-groups);
// blocks 64..71 = cross-attn MSE partials (independent of the max).
__global__ __launch_bounds__(256) void kmaxc(const float* __restrict__ attn,
                                             const float* __restrict__ attn_e,
                                             float* __restrict__ ws_maxpart,
                                             float* __restrict__ ws_crosspart) {
    const int t = threadIdx.x;
    if (blockIdx.x < 64) {
        __shared__ float tile[10 * 64];
        __shared__ float red[4];
        const int c = blockIdx.x >> 3;
        const int g = blockIdx.x & 7;
        const int tok = c + 1;
        const int ybase = 8 * g - 1;

        for (int idx = t; idx < 640; idx += 256) {
            int rr = idx >> 6, x = idx & 63;
            int y = min(max(ybase + rr, 0), 63);
            tile[idx] = attn[(y * 64 + x) * SEQ + tok];
        }
        __syncthreads();

        int x0, x1; float wx;
        coord(t, x0, x1, wx);
        float m = -1e30f;
        int cy0 = -99, cy1 = -99;
        float r0 = 0.f, r1 = 0.f;
        for (int i = 32 * g; i < 32 * g + 32; ++i) {
            int y0, y1; float wy;
            coord(i, y0, y1, wy);
            if (y0 != cy0 || y1 != cy1) {
                int l0 = y0 - ybase, l1 = y1 - ybase;
                if (y0 == cy1) r0 = r1;
                else r0 = tile[l0 * 64 + x0] * (1.f - wx) + tile[l0 * 64 + x1] * wx;
                if (y1 == y0) r1 = r0;
                else r1 = tile[l1 * 64 + x0] * (1.f - wx) + tile[l1 * 64 + x1] * wx;
                cy0 = y0; cy1 = y1;
            }
            m = fmaxf(m, r0 * (1.f - wy) + r1 * wy);
        }
        #pragma unroll
        for (int off = 1; off < 64; off <<= 1)
            m = fmaxf(m, __shfl_xor(m, off, 64));
        if ((t & 63) == 0) red[t >> 6] = m;
        __syncthreads();
        if (t == 0)
            ws_maxpart[blockIdx.x] = fmaxf(fmaxf(red[0], red[1]), fmaxf(red[2], red[3]));
    } else {
        __shared__ float red[4];
        const int tok = (int)blockIdx.x - 64 + 1;
        const bool is_tok = (tok == 2) || (tok == 5);
        float sum = 0.f;
        #pragma unroll
        for (int kk = 0; kk < 16; ++kk) {
            int p = t + kk * 256;
            float d = attn[p * SEQ + tok] - attn_e[p * SEQ + tok];
            sum += d * d;
        }
        #pragma unroll
        for (int off = 1; off < 64; off <<= 1) sum += __shfl_xor(sum, off, 64);
        if ((t & 63) == 0) red[t >> 6] = sum;
        __syncthreads();
        if (t == 0)
            ws_crosspart[tok - 1] =
                (is_tok ? -1.f : 1.f) * (red[0] + red[1] + red[2] + red[3]);
    }
}

// Kernel 2: 16 blocks write wj[j] = sum_c (+/-1)*gate[c,j] (full overwrite,
// no memset, no atomics).
__global__ __launch_bounds__(256) void kgates(const float* __restrict__ attn,
                                              const float* __restrict__ ws_maxpart,
                                              float* __restrict__ wj) {
    const int bid = blockIdx.x;
    const int t = threadIdx.x;
    const int j = bid * 256 + t;
    const int y = j >> 6, x = j & 63;
    float acc = 0.f;
    #pragma unroll
    for (int c = 0; c < 8; ++c) {
        const int tok = c + 1;
        const bool is_tok = (tok == 2) || (tok == 5);
        float mx = ws_maxpart[c * 8];
        #pragma unroll
        for (int g = 1; g < 8; ++g) mx = fmaxf(mx, ws_maxpart[c * 8 + g]);
        const float lim = mx * (is_tok ? 0.85f : 0.95f);
        bool gate = false;
        #pragma unroll
        for (int di = 1; di <= 2; ++di) {
            int y0, y1; float wy;
            coord(4 * y + di, y0, y1, wy);
            #pragma unroll
            for (int dj = 1; dj <= 2; ++dj) {
                int xa, xb; float wxv;
                coord(4 * x + dj, xa, xb, wxv);
                float v00 = attn[(y0 * 64 + xa) * SEQ + tok];
                float v01 = attn[(y0 * 64 + xb) * SEQ + tok];
                float v10 = attn[(y1 * 64 + xa) * SEQ + tok];
                float v11 = attn[(y1 * 64 + xb) * SEQ + tok];
                float top = v00 * (1.f - wxv) + v01 * wxv;
                float bot = v10 * (1.f - wxv) + v11 * wxv;
                float u = top * (1.f - wy) + bot * wy;
                gate = gate || (u >= lim);
            }
        }
        if (gate) acc += is_tok ? -1.f : 1.f;
    }
    wj[j] = acc;
}

// Kernel 3: streaming pass (r12-best): wj+row0 clause, row1 clause,
// vmcnt(8) split wait, nt loads, plain-store partial. NO fences, NO atomics.
__global__ __launch_bounds__(256) void kself(const float* __restrict__ a,
                                             const float* __restrict__ b,
                                             const float* __restrict__ wj,
                                             float* __restrict__ ws_partial) {
    __shared__ float red[4];
    const int t = threadIdx.x;
    const float* a0 = a + (size_t)blockIdx.x * 8192;
    const float* b0 = b + (size_t)blockIdx.x * 8192;
    const float* a1 = a0 + 4096;
    const float* b1 = b0 + 4096;
    const unsigned vo0 = (unsigned)t * 16u;
    const unsigned vo1 = vo0 + 4096u;
    const unsigned vo2 = vo0 + 8192u;
    const unsigned vo3 = vo0 + 12288u;
    f32x4 w0, w1, w2, w3, xa0, xa1, xa2, xa3, yb0, yb1, yb2, yb3;
    f32x4 xc0, xc1, xc2, xc3, yd0, yd1, yd2, yd3;
    asm volatile(   // blobA: wj (cached) + row0 (nt)
        "global_load_dwordx4 %0, %12, %16\n\t"
        "global_load_dwordx4 %1, %13, %16\n\t"
        "global_load_dwordx4 %2, %14, %16\n\t"
        "global_load_dwordx4 %3, %15, %16\n\t"
        "global_load_dwordx4 %4, %12, %17 nt\n\t"
        "global_load_dwordx4 %5, %13, %17 nt\n\t"
        "global_load_dwordx4 %6, %14, %17 nt\n\t"
        "global_load_dwordx4 %7, %15, %17 nt\n\t"
        "global_load_dwordx4 %8, %12, %18 nt\n\t"
        "global_load_dwordx4 %9, %13, %18 nt\n\t"
        "global_load_dwordx4 %10, %14, %18 nt\n\t"
        "global_load_dwordx4 %11, %15, %18 nt"
        : "=&v"(w0), "=&v"(w1), "=&v"(w2), "=&v"(w3),
          "=&v"(xa0), "=&v"(xa1), "=&v"(xa2), "=&v"(xa3),
          "=&v"(yb0), "=&v"(yb1), "=&v"(yb2), "=&v"(yb3)
        : "v"(vo0), "v"(vo1), "v"(vo2), "v"(vo3),
          "s"(wj), "s"(a0), "s"(b0));
    asm volatile(   // blobB: row1 (nt) + wait for wj+row0
        "global_load_dwordx4 %0, %8, %12 nt\n\t"
        "global_load_dwordx4 %1, %9, %12 nt\n\t"
        "global_load_dwordx4 %2, %10, %12 nt\n\t"
        "global_load_dwordx4 %3, %11, %12 nt\n\t"
        "global_load_dwordx4 %4, %8, %13 nt\n\t"
        "global_load_dwordx4 %5, %9, %13 nt\n\t"
        "global_load_dwordx4 %6, %10, %13 nt\n\t"
        "global_load_dwordx4 %7, %11, %13 nt\n\t"
        "s_waitcnt vmcnt(8)"
        : "=&v"(xc0), "=&v"(xc1), "=&v"(xc2), "=&v"(xc3),
          "=&v"(yd0), "=&v"(yd1), "=&v"(yd2), "=&v"(yd3)
        : "v"(vo0), "v"(vo1), "v"(vo2), "v"(vo3),
          "s"(a1), "s"(b1));
    __builtin_amdgcn_sched_barrier(0);
    float sum = 0.f;
    {   // row0
        float d0 = xa0.x - yb0.x, d1 = xa0.y - yb0.y, d2 = xa0.z - yb0.z, d3 = xa0.w - yb0.w;
        sum += w0.x * d0 * d0 + w0.y * d1 * d1 + w0.z * d2 * d2 + w0.w * d3 * d3;
        d0 = xa1.x - yb1.x; d1 = xa1.y - yb1.y; d2 = xa1.z - yb1.z; d3 = xa1.w - yb1.w;
        sum += w1.x * d0 * d0 + w1.y * d1 * d1 + w1.z * d2 * d2 + w1.w * d3 * d3;
        d0 = xa2.x - yb2.x; d1 = xa2.y - yb2.y; d2 = xa2.z - yb2.z; d3 = xa2.w - yb2.w;
        sum += w2.x * d0 * d0 + w2.y * d1 * d1 + w2.z * d2 * d2 + w2.w * d3 * d3;
        d0 = xa3.x - yb3.x; d1 = xa3.y - yb3.y; d2 = xa3.z - yb3.z; d3 = xa3.w - yb3.w;
        sum += w3.x * d0 * d0 + w3.y * d1 * d1 + w3.z * d2 * d2 + w3.w * d3 * d3;
    }
    asm volatile("s_waitcnt vmcnt(0)" ::: "memory");
    __builtin_amdgcn_sched_barrier(0);
    {   // row1 (same columns -> same w)
        float d0 = xc0.x - yd0.x, d1 = xc0.y - yd0.y, d2 = xc0.z - yd0.z, d3 = xc0.w - yd0.w;
        sum += w0.x * d0 * d0 + w0.y * d1 * d1 + w0.z * d2 * d2 + w0.w * d3 * d3;
        d0 = xc1.x - yd1.x; d1 = xc1.y - yd1.y; d2 = xc1.z - yd1.z; d3 = xc1.w - yd1.w;
        sum += w1.x * d0 * d0 + w1.y * d1 * d1 + w1.z * d2 * d2 + w1.w * d3 * d3;
        d0 = xc2.x - yd2.x; d1 = xc2.y - yd2.y; d2 = xc2.z - yd2.z; d3 = xc2.w - yd2.w;
        sum += w2.x * d0 * d0 + w2.y * d1 * d1 + w2.z * d2 * d2 + w2.w * d3 * d3;
        d0 = xc3.x - yd3.x; d1 = xc3.y - yd3.y; d2 = xc3.z - yd3.z; d3 = xc3.w - yd3.w;
        sum += w3.x * d0 * d0 + w3.y * d1 * d1 + w3.z * d2 * d2 + w3.w * d3 * d3;
    }
    #pragma unroll
    for (int off = 1; off < 64; off <<= 1) sum += __shfl_xor(sum, off, 64);
    if ((t & 63) == 0) red[t >> 6] = sum;
    __syncthreads();
    if (t == 0)
        ws_partial[blockIdx.x] = red[0] + red[1] + red[2] + red[3];
}

// Kernel 4: finalize — 1 block sums 2048 partials + 8 cross partials.
__global__ __launch_bounds__(256) void kfin(const float* __restrict__ ws_partial,
                                            const float* __restrict__ ws_crosspart,
                                            float* __restrict__ out) {
    __shared__ float red[4];
    const int t = threadIdx.x;
    float sum = 0.f;
    #pragma unroll
    for (int k = 0; k < 8; ++k) sum += ws_partial[t + k * 256];
    #pragma unroll
    for (int off = 1; off < 64; off <<= 1) sum += __shfl_xor(sum, off, 64);
    if ((t & 63) == 0) red[t >> 6] = sum;
    __syncthreads();
    if (t == 0) {
        float tot = red[0] + red[1] + red[2] + red[3];
        #pragma unroll
        for (int k = 0; k < 8; ++k) tot += ws_crosspart[k];
        out[0] = tot * (1.0f / HWPIX);
    }
}

extern "C" void kernel_launch(void* const* d_in, const int* in_sizes, int n_in,
                              void* d_out, int out_size, void* d_ws, size_t ws_size,
                              hipStream_t stream) {
    const float* attn   = (const float*)d_in[0];
    const float* attn_e = (const float*)d_in[1];
    const float* sa     = (const float*)d_in[2];
    const float* sae    = (const float*)d_in[3];
    float* out = (float*)d_out;
    float* wj      = (float*)d_ws;          // [0,    4096) gate weights (overwritten)
    float* ws_maxp = wj + HWPIX;            // [4096, 4160) 64 max partials
    float* ws_crop = wj + 4160;             // [4160, 4168) 8 cross partials
    float* ws_part = wj + 4352;             // [4352, 6400) kself partials (2048)

    // 4 launches; no memsets, no atomics, no fences: every ws location read
    // is written earlier in the same replay by a plain store.
    kmaxc <<<72,        256, 0, stream>>>(attn, attn_e, ws_maxp, ws_crop);
    kgates<<<16,        256, 0, stream>>>(attn, ws_maxp, wj);
    kself <<<NBLK_SELF, 256, 0, stream>>>(sa, sae, wj, ws_part);
    kfin  <<<1,         256, 0, stream>>>(ws_part, ws_crop, out);
}